// Round 2
// 332.902 us; speedup vs baseline: 1.2200x; 1.2200x over previous
//
#include <hip/hip_runtime.h>

// B=8, H=W=256, I_DIM=64, K_DIM=64 (hd_k=32), V_DIM=32 (hd_v=16), O_DIM=64
// NH=2, unfold: p=7, stride=21, dilation=4, npw=12 -> S=144 patches
#define BB 8
#define HH 256
#define CIN 64
#define NPW 12
#define SPP 144
#define PP 49
#define PDIM 7
#define STRIDE 21
#define DIL 4
#define NS 84

typedef __attribute__((ext_vector_type(8))) short bf16x8;
typedef __attribute__((ext_vector_type(4))) float f32x4;

#define MFMA(a, b, c) __builtin_amdgcn_mfma_f32_16x16x32_bf16((a), (b), (c), 0, 0, 0)

static __device__ __forceinline__ unsigned short f2bf(float f) {
  union { float f; unsigned u; } v; v.f = f;
  unsigned r = (v.u + 0x7fffu + ((v.u >> 16) & 1u)) >> 16;
  return (unsigned short)r;
}
static __device__ __forceinline__ float bf2f(unsigned short h) {
  union { unsigned u; float f; } v; v.u = ((unsigned)h) << 16;
  return v.f;
}
static __device__ __forceinline__ unsigned pk2(float a, float b) {
  return (unsigned)f2bf(a) | ((unsigned)f2bf(b) << 16);
}

// ---------------------------------------------------------------------------
// Kernel 1: one block per (b, patch), 4 waves, all matmul phases on MFMA.
// MFMA 16x16x32 bf16 layout (learn_hip verified):
//   A: lane&15 = m-row, k = (lane>>4)*8 + j (8 contiguous k, ds_read_b128)
//   B: lane&15 = n-col, k = (lane>>4)*8 + j (contiguous k per col)
//   D: col = lane&15, row = (lane>>4)*4 + reg
// LDS 46080 B -> 3 blocks/CU.
// ---------------------------------------------------------------------------
__global__ __launch_bounds__(256, 3) void k1_fused(
    const float* __restrict__ x1, const float* __restrict__ x2,
    const float* __restrict__ Wk, const float* __restrict__ bk,
    const float* __restrict__ Wv, const float* __restrict__ bv,
    const float* __restrict__ Wp, float* __restrict__ P)
{
  // uA: ph0-1 XT[2][64][64] (t-row, c-contig, XOR-swz 16B granules)
  //     ph2+  kkb[2][64][72] bf16 logits, row x, col y (stride 72 -> 16B aligned)
  __shared__ __align__(16) short uA[9216];
  // uB: ph1-2 KT[64][136]  (KV transposed: row t, col r; r<128 = K1|K2)
  //     ph5+  OT[64][72]   (row t, col l = output channel of o-concat)
  __shared__ __align__(16) short uB[8704];
  // V[64][64]: rows 0..31 = V1 (head-major), 32..63 = V2; XOR-swz 16B granules
  __shared__ __align__(16) short sV[4096];
  __shared__ float sStat[4][2][64];   // 0:cmax 1:1/csum 2:rmax 3:1/rsum

  const int tid = threadIdx.x;
  const int lane = tid & 63;
  const int wid = tid >> 6;
  const int l16 = lane & 15;
  const int l4 = lane >> 4;
  const int blk = blockIdx.x;
  const int b  = blk / SPP;
  const int sp = blk % SPP;
  const int pi = sp / NPW, pj = sp % NPW;
  const int h0 = pi * STRIDE, w0 = pj * STRIDE;

  // ---- phase 0: gather x tiles into XT (bf16, transposed, swizzled) ----
  for (int i = tid; i < 2 * CIN * PP; i += 256) {
    int src = i / (CIN * PP);
    int r = i - src * (CIN * PP);
    int c = r / PP, t = r - c * PP;
    int ph = t / PDIM, pw = t - ph * PDIM;
    const float* xp = src ? x2 : x1;
    float v = xp[(((size_t)b * CIN + c) * HH + (h0 + ph * DIL)) * HH + (w0 + pw * DIL)];
    uA[(src * 64 + t) * 64 + ((((c >> 3) ^ (t & 7)) << 3) | (c & 7))] = (short)f2bf(v);
  }
  // zero pad rows t=49..63 (MFMA pads must be finite-zero: 0*finite = 0)
  for (int i = tid; i < 2 * 15 * 64; i += 256) {
    int src = i / (15 * 64);
    int r = i - src * 15 * 64;
    int t = 49 + (r >> 6);
    int c = r & 63;
    uA[(src * 64 + t) * 64 + c] = 0;
  }
  __syncthreads();

  // ---- phase 1: projections KV[192][64px] = W(hi+lo) @ XT, MFMA ----
  // Mtiles: 0-3 K1(x1), 4-7 K2(x2), 8-9 V1(x1), 10-11 V2(x2). Wave w: 3w..3w+2.
  {
    #pragma unroll
    for (int mi = 0; mi < 3; mi++) {
      const int m = wid * 3 + mi;
      const int r0 = m * 16;
      const int src = (m < 4) ? 0 : (m < 8 ? 1 : (m < 10 ? 0 : 1));
      const int rl = r0 + l16;
      const float* wrow = (r0 < 128) ? (Wk + (size_t)rl * 64)
                                     : (Wv + (size_t)(rl - 128) * 64);
      bf16x8 ahi[2], alo[2];
      #pragma unroll
      for (int kt = 0; kt < 2; kt++) {
        const float* wp8 = wrow + kt * 32 + l4 * 8;
        float4 wa = *(const float4*)wp8;
        float4 wb = *(const float4*)(wp8 + 4);
        float wf[8] = {wa.x, wa.y, wa.z, wa.w, wb.x, wb.y, wb.z, wb.w};
        #pragma unroll
        for (int j = 0; j < 8; j++) {
          unsigned short h = f2bf(wf[j]);
          ahi[kt][j] = (short)h;
          alo[kt][j] = (short)f2bf(wf[j] - bf2f(h));
        }
      }
      float bias[4];
      #pragma unroll
      for (int i = 0; i < 4; i++) {
        int rd = r0 + l4 * 4 + i;
        bias[i] = (r0 < 128) ? bk[rd] : bv[rd - 128];
      }
      #pragma unroll
      for (int nt = 0; nt < 4; nt++) {
        const int t = nt * 16 + l16;
        f32x4 acc = {0.f, 0.f, 0.f, 0.f};
        #pragma unroll
        for (int kt = 0; kt < 2; kt++) {
          bf16x8 xb = *(const bf16x8*)
              &uA[(src * 64 + t) * 64 + ((((kt << 2) + l4) ^ (t & 7)) << 3)];
          acc = MFMA(alo[kt], xb, acc);
          acc = MFMA(ahi[kt], xb, acc);
        }
        if (r0 < 128) {
          // KT[t][r0 + l4*4 .. +3] packed bf16 (8B store)
          unsigned* p = (unsigned*)&uB[t * 136 + r0 + l4 * 4];
          p[0] = pk2(acc[0] + bias[0], acc[1] + bias[1]);
          p[1] = pk2(acc[2] + bias[2], acc[3] + bias[3]);
        } else {
          #pragma unroll
          for (int i = 0; i < 4; i++) {
            int rv = r0 - 128 + l4 * 4 + i;
            sV[rv * 64 + ((((t >> 3) ^ (rv & 7)) << 3) | (t & 7))] =
                (short)f2bf(acc[i] + bias[i]);
          }
        }
      }
    }
  }
  __syncthreads();   // XT dead; uA becomes kkb

  const float scale = 0.17677669529663687f;  // 1/sqrt(32)

  // ---- phase 2: logits kk[n][x][y] = scale * K1^T K2, one MFMA per tile ----
  // wave w: head n = w>>1, x-tiles {(w&1)*2, (w&1)*2+1}, all 4 y-tiles
  {
    const int n = wid >> 1;
    #pragma unroll
    for (int xi = 0; xi < 2; xi++) {
      const int x0 = ((wid & 1) * 2 + xi) * 16;
      bf16x8 a = *(const bf16x8*)&uB[(x0 + l16) * 136 + n * 32 + l4 * 8];
      #pragma unroll
      for (int yt = 0; yt < 4; yt++) {
        const int y = yt * 16 + l16;
        bf16x8 bb = *(const bf16x8*)&uB[y * 136 + 64 + n * 32 + l4 * 8];
        f32x4 acc = {0.f, 0.f, 0.f, 0.f};
        acc = MFMA(a, bb, acc);
        #pragma unroll
        for (int i = 0; i < 4; i++) {
          int x = x0 + l4 * 4 + i;
          uA[(n * 64 + x) * 72 + y] = (short)f2bf(acc[i] * scale);
        }
      }
    }
  }
  __syncthreads();

  // ---- phase 3: softmax stats (col over x for each y; row over y for each x)
  if (tid < 196) {
    int n = tid / 98;
    int r = tid % 98;
    int isRow = r >= 49;
    int j = r - (isRow ? 49 : 0);
    float mx = -1e30f;
    for (int k = 0; k < 49; k++) {
      float v = bf2f((unsigned short)uA[(n * 64 + (isRow ? j : k)) * 72 + (isRow ? k : j)]);
      mx = fmaxf(mx, v);
    }
    float sm = 0.f;
    for (int k = 0; k < 49; k++) {
      float v = bf2f((unsigned short)uA[(n * 64 + (isRow ? j : k)) * 72 + (isRow ? k : j)]);
      sm += __expf(v - mx);
    }
    int kind = isRow ? 2 : 0;
    sStat[kind][n][j] = mx;
    sStat[kind + 1][n][j] = 1.0f / sm;
  }
  __syncthreads();   // KT dead; uB becomes OT

  // ---- phase 5: AV via MFMA, exp built in-register into B-fragments ----
  // wave w: head n = w>>1, side = w&1.
  // side0: O[n*16+d][t] = (1/csum[t]) * sum_x exp(kk[x][t]-cmax[t]) * V1[d][x]
  // side1: O[32+n*16+d][x] = (1/rsum[x]) * sum_y exp(kk[x][y]-rmax[x]) * V2[d][y]
  {
    const int n = wid >> 1;
    const int side = wid & 1;
    const int rv = side * 32 + n * 16 + l16;
    bf16x8 av[2];
    #pragma unroll
    for (int kt = 0; kt < 2; kt++)
      av[kt] = *(const bf16x8*)&sV[rv * 64 + ((((kt << 2) + l4) ^ (rv & 7)) << 3)];
    if (side == 0) {
      #pragma unroll
      for (int tt = 0; tt < 4; tt++) {
        const int t = tt * 16 + l16;
        const float cm = sStat[0][n][t], cs = sStat[1][n][t];
        f32x4 acc = {0.f, 0.f, 0.f, 0.f};
        #pragma unroll
        for (int kt = 0; kt < 2; kt++) {
          bf16x8 bfrag;
          #pragma unroll
          for (int j = 0; j < 8; j++) {
            const int x = kt * 32 + l4 * 8 + j;
            float v = bf2f((unsigned short)uA[(n * 64 + x) * 72 + t]);
            float e = (x < PP) ? __expf(v - cm) : 0.f;
            bfrag[j] = (short)f2bf(e);
          }
          acc = MFMA(av[kt], bfrag, acc);
        }
        unsigned* p = (unsigned*)&uB[t * 72 + n * 16 + l4 * 4];
        p[0] = pk2(acc[0] * cs, acc[1] * cs);
        p[1] = pk2(acc[2] * cs, acc[3] * cs);
      }
    } else {
      #pragma unroll
      for (int xt = 0; xt < 4; xt++) {
        const int x = xt * 16 + l16;
        const float rm = sStat[2][n][x], rs = sStat[3][n][x];
        f32x4 acc = {0.f, 0.f, 0.f, 0.f};
        #pragma unroll
        for (int kt = 0; kt < 2; kt++) {
          bf16x8 braw = *(const bf16x8*)&uA[(n * 64 + x) * 72 + kt * 32 + l4 * 8];
          bf16x8 bfrag;
          #pragma unroll
          for (int j = 0; j < 8; j++) {
            const int y = kt * 32 + l4 * 8 + j;
            float v = bf2f((unsigned short)braw[j]);
            float e = (y < PP) ? __expf(v - rm) : 0.f;
            bfrag[j] = (short)f2bf(e);
          }
          acc = MFMA(av[kt], bfrag, acc);
        }
        unsigned* p = (unsigned*)&uB[x * 72 + 32 + n * 16 + l4 * 4];
        p[0] = pk2(acc[0] * rs, acc[1] * rs);
        p[1] = pk2(acc[2] * rs, acc[3] * rs);
      }
    }
  }
  __syncthreads();

  // ---- phase 6: out-proj P[oc][t] = Wp(hi+lo) @ OT, wave w owns oc-tile w ----
  {
    const float* wrow = Wp + (size_t)(wid * 16 + l16) * 64;
    bf16x8 whi[2], wlo[2];
    #pragma unroll
    for (int kt = 0; kt < 2; kt++) {
      const float* wp8 = wrow + kt * 32 + l4 * 8;
      float4 wa = *(const float4*)wp8;
      float4 wb = *(const float4*)(wp8 + 4);
      float wf[8] = {wa.x, wa.y, wa.z, wa.w, wb.x, wb.y, wb.z, wb.w};
      #pragma unroll
      for (int j = 0; j < 8; j++) {
        unsigned short h = f2bf(wf[j]);
        whi[kt][j] = (short)h;
        wlo[kt][j] = (short)f2bf(wf[j] - bf2f(h));
      }
    }
    #pragma unroll
    for (int tt = 0; tt < 4; tt++) {
      const int t = tt * 16 + l16;
      f32x4 acc = {0.f, 0.f, 0.f, 0.f};
      #pragma unroll
      for (int kt = 0; kt < 2; kt++) {
        bf16x8 ob = *(const bf16x8*)&uB[t * 72 + kt * 32 + l4 * 8];
        acc = MFMA(wlo[kt], ob, acc);
        acc = MFMA(whi[kt], ob, acc);
      }
      if (t < PP) {
        const int ph = t / 7, pw = t - ph * 7;
        const size_t col = (size_t)(pi * 7 + ph) * NS + (pj * 7 + pw);
        #pragma unroll
        for (int i = 0; i < 4; i++) {
          const int oc = wid * 16 + l4 * 4 + i;
          P[((size_t)b * 64 + oc) * (NS * NS) + col] = acc[i];
        }
      }
    }
  }
}

// ---------------------------------------------------------------------------
// Kernel 2: merge. out[b][oc][h][w] = bp[oc] + (sampled ? P : 0). float4.
// ---------------------------------------------------------------------------
__global__ __launch_bounds__(256) void k2_merge(
    const float* __restrict__ P, const float* __restrict__ bp,
    float* __restrict__ out)
{
  __shared__ float bps[64];
  __shared__ int wsmap[256];
  const int tid = threadIdx.x;
  const int b = blockIdx.x / HH, h = blockIdx.x % HH;
  if (tid < 64) bps[tid] = bp[tid];
  {
    int w = tid, wsv = -1;
    for (int pj = 0; pj < NPW; pj++) {
      int r = w - pj * STRIDE;
      if (r >= 0 && r <= (PDIM - 1) * DIL && (r % DIL) == 0) { wsv = pj * PDIM + r / DIL; break; }
    }
    wsmap[tid] = wsv;
  }
  int hs = -1;
  for (int pi = 0; pi < NPW; pi++) {
    int r = h - pi * STRIDE;
    if (r >= 0 && r <= (PDIM - 1) * DIL && (r % DIL) == 0) { hs = pi * PDIM + r / DIL; break; }
  }
  __syncthreads();

  const int wq = tid & 63;   // float4 column
  const int ocq = tid >> 6;  // 0..3
  float4* out4 = (float4*)out;

  if (hs < 0) {
    #pragma unroll 4
    for (int oc = ocq; oc < 64; oc += 4) {
      float bv = bps[oc];
      out4[(((size_t)b * 64 + oc) * HH + h) * 64 + wq] = make_float4(bv, bv, bv, bv);
    }
    return;
  }
  const int ws0 = wsmap[wq * 4 + 0], ws1 = wsmap[wq * 4 + 1];
  const int ws2 = wsmap[wq * 4 + 2], ws3 = wsmap[wq * 4 + 3];
  #pragma unroll 4
  for (int oc = ocq; oc < 64; oc += 4) {
    float bv = bps[oc];
    size_t rbase = (((size_t)b * 64 + oc) * NS + hs) * NS;
    float4 v = make_float4(bv, bv, bv, bv);
    if (ws0 >= 0) v.x += P[rbase + ws0];
    if (ws1 >= 0) v.y += P[rbase + ws1];
    if (ws2 >= 0) v.z += P[rbase + ws2];
    if (ws3 >= 0) v.w += P[rbase + ws3];
    out4[(((size_t)b * 64 + oc) * HH + h) * 64 + wq] = v;
  }
}

extern "C" void kernel_launch(void* const* d_in, const int* in_sizes, int n_in,
                              void* d_out, int out_size, void* d_ws, size_t ws_size,
                              hipStream_t stream) {
  const float* x1 = (const float*)d_in[0];
  const float* x2 = (const float*)d_in[1];
  const float* Wk = (const float*)d_in[2];
  const float* bk = (const float*)d_in[3];
  const float* Wv = (const float*)d_in[4];
  const float* bv = (const float*)d_in[5];
  const float* Wp = (const float*)d_in[6];
  const float* bp = (const float*)d_in[7];
  float* P = (float*)d_ws;  // 8*64*84*84 floats = 14.45 MB
  float* out = (float*)d_out;

  k1_fused<<<dim3(BB * SPP), dim3(256), 0, stream>>>(x1, x2, Wk, bk, Wv, bv, Wp, P);
  k2_merge<<<dim3(BB * HH), dim3(256), 0, stream>>>(P, bp, out);
}